// Round 14
// baseline (120.196 us; speedup 1.0000x reference)
//
#include <hip/hip_runtime.h>

typedef __attribute__((ext_vector_type(4))) float f32x4;
typedef __bf16 bf16x8 __attribute__((ext_vector_type(8)));
typedef unsigned short ushort_t;

#define T_TOK 8192   // B*S
#define DIM   1024   // D
#define NRCOL 2048   // N_FEAT * R

#define VMW(n)  asm volatile("s_waitcnt vmcnt(" #n ")" ::: "memory")
#define SB0()   __builtin_amdgcn_sched_barrier(0)
#define BAR()   __builtin_amdgcn_s_barrier()

static __device__ __forceinline__ unsigned short f2bf(float f) {
  unsigned int u = __builtin_bit_cast(unsigned int, f);
  u += 0x7fffu + ((u >> 16) & 1u);          // RNE
  return (unsigned short)(u >> 16);
}
static __device__ __forceinline__ float bfbits2f(unsigned int lo16) {
  return __builtin_bit_cast(float, lo16 << 16);
}
static __device__ __forceinline__ void gload16(const void* g, void* l) {
  __builtin_amdgcn_global_load_lds((const __attribute__((address_space(1))) void*)g,
                                   (__attribute__((address_space(3))) void*)l, 16, 0, 0);
}

// ---------------- fused prep: x cast + fk transpose + rk transpose ----------------
__global__ __launch_bounds__(256) void prep_kernel(const float* __restrict__ x,
                                                   const float* __restrict__ fk,
                                                   const float* __restrict__ rk,
                                                   unsigned short* __restrict__ Xbf,
                                                   unsigned short* __restrict__ W1t,
                                                   unsigned short* __restrict__ W2t) {
  const int bid = blockIdx.x, tid = threadIdx.x;
  if (bid < 2048) {
    const float4* in4 = (const float4*)x;
    uint2* o4 = (uint2*)Xbf;
    #pragma unroll
    for (int it = 0; it < 4; ++it) {
      const int i = bid * 256 + tid + it * 524288;
      float4 v = in4[i];
      uint2 o;
      o.x = (unsigned)f2bf(v.x) | ((unsigned)f2bf(v.y) << 16);
      o.y = (unsigned)f2bf(v.z) | ((unsigned)f2bf(v.w) << 16);
      o4[i] = o;
    }
    return;
  }
  __shared__ float tile[32][33];
  const float* src;
  unsigned short* dst;
  int rows, cols, r0, c0;
  if (bid < 4096) {                 // fk [16][1024][128] -> W1t per-z [128][1024]
    const int b = bid - 2048;
    const int z = b >> 7, rem = b & 127;
    src = fk + (size_t)z * 1024 * 128;
    dst = W1t + (size_t)z * 128 * 1024;
    rows = 1024; cols = 128;
    c0 = (rem & 3) * 32; r0 = (rem >> 2) * 32;
  } else {                          // rk [2048][1024] -> W2t [1024][2048]
    const int b = bid - 4096;
    src = rk; dst = W2t;
    rows = 2048; cols = 1024;
    c0 = (b & 31) * 32; r0 = (b >> 5) * 32;
  }
  const int tx = tid & 31, ty = tid >> 5;
  #pragma unroll
  for (int i = 0; i < 32; i += 8)
    tile[ty + i][tx] = src[(size_t)(r0 + ty + i) * cols + c0 + tx];
  __syncthreads();
  #pragma unroll
  for (int i = 0; i < 32; i += 8)
    dst[(size_t)(c0 + ty + i) * rows + r0 + tx] = f2bf(tile[tx][ty + i]);
}

// =====================================================================
// gemmS: C[M,N] = A[M,K]*Bt[N,K]^T. m97-class config: 128x128 tile,
// BK=64, 256 thr = 4 waves (2x2, wave 64x64), SINGLE 32 KB LDS buffer,
// 2 barriers per K-tile, NO prefetch/dbuf. 88 VGPR + 32 KB LDS ->
// ~5 independent blocks/CU (5 waves/SIMD): inter-block TLP hides the
// stage/vmcnt/barrier stalls (m114/m132 mechanism) that lockstep
// 1-2-block configs could not. Ledger: reads of tile t-1 retire before
// the end-BAR (MFMA reg-deps drain lgkm), so stage(t)'s overwrite is
// WAR-safe; VMW(0)+BAR covers RAW. Swizzles = measured conflict-free.
// =====================================================================
template<int K, bool OUT_BF16>
__global__ __launch_bounds__(256) void gemmS(const ushort_t* __restrict__ A,
                                             const ushort_t* __restrict__ Bt,
                                             void* __restrict__ Cp, int N) {
  constexpr int nt = K / 64;
  __shared__ ushort_t As[128 * 64];
  __shared__ ushort_t Bs[128 * 64];

  const int tid = threadIdx.x;
  const int nx = gridDim.x;
  const int orig = blockIdx.y * nx + blockIdx.x;
  const int q = (nx * gridDim.y) >> 3;     // grids are multiples of 8
  const int swz = (orig & 7) * q + (orig >> 3);
  const int bx = swz % nx, by = swz / nx;

  const int lane = tid & 63, wv = tid >> 6;
  const int wm = wv >> 1, wn = wv & 1;     // 2M x 2N
  const int lrow = lane & 15, lk = lane >> 4;

  const ushort_t* Ab = A + (size_t)by * 128 * K;
  const ushort_t* Bb = Bt + (size_t)bx * 128 * K;

  // staging: 4 A rounds + 4 B rounds, 32 rows x 128 B each
  const int srow = tid >> 3;
  const int sch = (tid & 7) ^ (srow & 7);
  const ushort_t* pA[4];
  const ushort_t* pB[4];
  #pragma unroll
  for (int r = 0; r < 4; ++r) {
    pA[r] = Ab + (size_t)(r * 32 + srow) * K + sch * 8;
    pB[r] = Bb + (size_t)(r * 32 + srow) * K + sch * 8;
  }
  const int dL = tid * 8;                  // LDS dest elems (+ r*2048)

  // frag base offsets (ks=1 folds in as ^32 elems; verified pattern)
  int oA[4], oB[4];
  #pragma unroll
  for (int m = 0; m < 4; ++m) {
    const int r = wm * 64 + m * 16 + lrow;
    oA[m] = r * 64 + (lk ^ (r & 7)) * 8;
  }
  #pragma unroll
  for (int n = 0; n < 4; ++n) {
    const int r = wn * 64 + n * 16 + lrow;
    oB[n] = r * 64 + (lk ^ (r & 7)) * 8;
  }

  f32x4 acc[4][4];
  #pragma unroll
  for (int m = 0; m < 4; ++m)
    #pragma unroll
    for (int n = 0; n < 4; ++n)
      acc[m][n] = (f32x4){0.f, 0.f, 0.f, 0.f};

  #pragma unroll 1
  for (int t = 0; t < nt; ++t) {
    // stage tile t (single buffer)
    #pragma unroll
    for (int r = 0; r < 4; ++r) gload16(pA[r] + t * 64, (void*)&As[r * 2048 + dL]);
    #pragma unroll
    for (int r = 0; r < 4; ++r) gload16(pB[r] + t * 64, (void*)&Bs[r * 2048 + dL]);
    VMW(0); SB0();
    BAR(); SB0();
    #pragma unroll
    for (int ks = 0; ks < 2; ++ks) {
      bf16x8 av[4], bv[4];
      #pragma unroll
      for (int m = 0; m < 4; ++m) av[m] = *(const bf16x8*)&As[oA[m] ^ (ks * 32)];
      #pragma unroll
      for (int n = 0; n < 4; ++n) bv[n] = *(const bf16x8*)&Bs[oB[n] ^ (ks * 32)];
      #pragma unroll
      for (int m = 0; m < 4; ++m)
        #pragma unroll
        for (int n = 0; n < 4; ++n)
          acc[m][n] = __builtin_amdgcn_mfma_f32_16x16x32_bf16(av[m], bv[n], acc[m][n], 0, 0, 0);
    }
    SB0();
    BAR(); SB0();                    // all reads retired -> next stage WAR-safe
  }

  // epilogue: C/D layout col=lane&15, row=(lane>>4)*4+j
  #pragma unroll
  for (int m = 0; m < 4; ++m) {
    const int row0 = by * 128 + wm * 64 + m * 16 + lk * 4;
    #pragma unroll
    for (int n = 0; n < 4; ++n) {
      const int col = bx * 128 + wn * 64 + n * 16 + lrow;
      #pragma unroll
      for (int j = 0; j < 4; ++j) {
        const size_t idx = (size_t)(row0 + j) * N + col;
        if constexpr (OUT_BF16) ((ushort_t*)Cp)[idx] = f2bf(acc[m][n][j]);
        else                    ((float*)Cp)[idx] = acc[m][n][j];
      }
    }
  }
}

// ---------------- middle: h_all, router softmax, M = sum_p w (x) h ----------------
__global__ __launch_bounds__(256) void middle_kernel(const unsigned short* __restrict__ AH,
                                                     const float* __restrict__ fp,
                                                     const float* __restrict__ femb,
                                                     const float* __restrict__ Wr,
                                                     unsigned short* __restrict__ Mout,
                                                     float* __restrict__ auxout) {
  __shared__ float G[16][16];
  __shared__ float WrBs[128 * 16];
  __shared__ float hs[4][2][128];
  __shared__ float wsm[4][2][16];
  const int tid = threadIdx.x;
  {
    const int n = tid >> 4, j = tid & 15;
    float s = 0.f;
    #pragma unroll
    for (int ds = 0; ds < 64; ++ds) s += femb[n * 64 + ds] * Wr[ds * 16 + j];
    G[n][j] = s;
    #pragma unroll
    for (int k = 0; k < 8; ++k)
      WrBs[tid * 8 + k] = Wr[64 * 16 + tid * 8 + k];
  }
  const int wv = tid >> 6, l = tid & 63;
  const int t = blockIdx.x * 4 + wv;

  float p0[16], p1[16];
  #pragma unroll
  for (int n = 0; n < 16; ++n) {
    p0[n] = fp[t * 16 + n];
    p1[n] = fp[T_TOK * 16 + t * 16 + n];
  }

  float h00 = 0.f, h01 = 0.f, h10 = 0.f, h11 = 0.f;
  const unsigned short* ahrow = AH + (size_t)t * NRCOL;
  #pragma unroll
  for (int n = 0; n < 16; ++n) {
    const unsigned int v = *(const unsigned int*)(ahrow + n * 128 + 2 * l);
    const float a0 = bfbits2f(v & 0xffffu);
    const float a1 = bfbits2f(v >> 16);
    h00 += a0 * p0[n]; h01 += a1 * p0[n];
    h10 += a0 * p1[n]; h11 += a1 * p1[n];
  }
  hs[wv][0][2 * l] = h00; hs[wv][0][2 * l + 1] = h01;
  hs[wv][1][2 * l] = h10; hs[wv][1][2 * l + 1] = h11;
  __syncthreads();

  {
    const int p = l >> 5, seg = (l >> 4) & 1, j = l & 15;
    const float* hp = hs[wv][p] + seg * 64;
    const float* wb = WrBs + seg * 64 * 16 + j;
    float s0 = 0.f, s1 = 0.f, s2 = 0.f, s3 = 0.f;
    #pragma unroll
    for (int r = 0; r < 64; r += 4) {
      s0 += hp[r]     * wb[(r)     * 16];
      s1 += hp[r + 1] * wb[(r + 1) * 16];
      s2 += hp[r + 2] * wb[(r + 2) * 16];
      s3 += hp[r + 3] * wb[(r + 3) * 16];
    }
    float s = (s0 + s1) + (s2 + s3);
    s += __shfl_xor(s, 16, 64);          // combine r-segments
    #pragma unroll
    for (int n = 0; n < 16; ++n) {
      const float fv = p ? p1[n] : p0[n];
      s += fv * G[n][j];
    }
    float mx = s;
    #pragma unroll
    for (int d = 1; d < 16; d <<= 1) mx = fmaxf(mx, __shfl_xor(mx, d, 64));
    const float e = __expf(s - mx);
    float sum = e;
    #pragma unroll
    for (int d = 1; d < 16; d <<= 1) sum += __shfl_xor(sum, d, 64);
    if (seg == 0) wsm[wv][p][j] = e / sum;
  }
  __syncthreads();

  unsigned short* mrow = Mout + (size_t)t * NRCOL;
  #pragma unroll
  for (int n = 0; n < 16; ++n) {
    const float w0 = wsm[wv][0][n], w1 = wsm[wv][1][n];
    const float m0 = w0 * h00 + w1 * h10;
    const float m1 = w0 * h01 + w1 * h11;
    const unsigned int pk = (unsigned)f2bf(m0) | ((unsigned)f2bf(m1) << 16);
    *(unsigned int*)(mrow + n * 128 + 2 * l) = pk;
  }
  if (blockIdx.x == 0 && tid == 0) auxout[0] = 0.f;
}

extern "C" void kernel_launch(void* const* d_in, const int* in_sizes, int n_in,
                              void* d_out, int out_size, void* d_ws, size_t ws_size,
                              hipStream_t stream) {
  const float* x    = (const float*)d_in[0];
  const float* fp   = (const float*)d_in[1];
  const float* fk   = (const float*)d_in[2];
  const float* rk   = (const float*)d_in[3];
  const float* femb = (const float*)d_in[4];
  const float* Wr   = (const float*)d_in[5];
  float* out = (float*)d_out;

  char* ws = (char*)d_ws;
  unsigned short* Xbf = (unsigned short*)ws;
  unsigned short* W1t = (unsigned short*)(ws + 16u * 1024 * 1024);
  unsigned short* Mb  = (unsigned short*)ws;
  unsigned short* W2t = (unsigned short*)(ws + 32u * 1024 * 1024);
  unsigned short* AH  = (unsigned short*)(ws + 36u * 1024 * 1024);

  prep_kernel<<<6144, 256, 0, stream>>>(x, fk, rk, Xbf, W1t, W2t);
  // all_h = Xbf @ W1t^T -> AH bf16 [8192][2048]   (128x128, ~5 blocks/CU)
  gemmS<1024, true><<<dim3(NRCOL / 128, T_TOK / 128), 256, 0, stream>>>(Xbf, W1t, AH, NRCOL);
  middle_kernel<<<T_TOK / 4, 256, 0, stream>>>(AH, fp, femb, Wr, Mb, out + 8388608);
  // output = Mb @ W2t^T -> f32 d_out [8192][1024] (128x128, ~5 blocks/CU)
  gemmS<2048, false><<<dim3(DIM / 128, T_TOK / 128), 256, 0, stream>>>(Mb, W2t, out, DIM);
}

// Round 15
// 107.604 us; speedup vs baseline: 1.1170x; 1.1170x over previous
//
#include <hip/hip_runtime.h>

typedef __attribute__((ext_vector_type(4))) float f32x4;
typedef __bf16 bf16x8 __attribute__((ext_vector_type(8)));
typedef unsigned short ushort_t;

#define T_TOK 8192   // B*S
#define DIM   1024   // D
#define NRCOL 2048   // N_FEAT * R

#define VMW(n)  asm volatile("s_waitcnt vmcnt(" #n ")" ::: "memory")
#define SB0()   __builtin_amdgcn_sched_barrier(0)
#define BAR()   __builtin_amdgcn_s_barrier()

static __device__ __forceinline__ unsigned short f2bf(float f) {
  unsigned int u = __builtin_bit_cast(unsigned int, f);
  u += 0x7fffu + ((u >> 16) & 1u);          // RNE
  return (unsigned short)(u >> 16);
}
static __device__ __forceinline__ float bfbits2f(unsigned int lo16) {
  return __builtin_bit_cast(float, lo16 << 16);
}
static __device__ __forceinline__ void gload16(const void* g, void* l) {
  __builtin_amdgcn_global_load_lds((const __attribute__((address_space(1))) void*)g,
                                   (__attribute__((address_space(3))) void*)l, 16, 0, 0);
}

// ---------------- fused prep: x cast + fk transpose + rk transpose ----------------
__global__ __launch_bounds__(256) void prep_kernel(const float* __restrict__ x,
                                                   const float* __restrict__ fk,
                                                   const float* __restrict__ rk,
                                                   unsigned short* __restrict__ Xbf,
                                                   unsigned short* __restrict__ W1t,
                                                   unsigned short* __restrict__ W2t) {
  const int bid = blockIdx.x, tid = threadIdx.x;
  if (bid < 2048) {
    const float4* in4 = (const float4*)x;
    uint2* o4 = (uint2*)Xbf;
    #pragma unroll
    for (int it = 0; it < 4; ++it) {
      const int i = bid * 256 + tid + it * 524288;
      float4 v = in4[i];
      uint2 o;
      o.x = (unsigned)f2bf(v.x) | ((unsigned)f2bf(v.y) << 16);
      o.y = (unsigned)f2bf(v.z) | ((unsigned)f2bf(v.w) << 16);
      o4[i] = o;
    }
    return;
  }
  __shared__ float tile[32][33];
  const float* src;
  unsigned short* dst;
  int rows, cols, r0, c0;
  if (bid < 4096) {                 // fk [16][1024][128] -> W1t per-z [128][1024]
    const int b = bid - 2048;
    const int z = b >> 7, rem = b & 127;
    src = fk + (size_t)z * 1024 * 128;
    dst = W1t + (size_t)z * 128 * 1024;
    rows = 1024; cols = 128;
    c0 = (rem & 3) * 32; r0 = (rem >> 2) * 32;
  } else {                          // rk [2048][1024] -> W2t [1024][2048]
    const int b = bid - 4096;
    src = rk; dst = W2t;
    rows = 2048; cols = 1024;
    c0 = (b & 31) * 32; r0 = (b >> 5) * 32;
  }
  const int tx = tid & 31, ty = tid >> 5;
  #pragma unroll
  for (int i = 0; i < 32; i += 8)
    tile[ty + i][tx] = src[(size_t)(r0 + ty + i) * cols + c0 + tx];
  __syncthreads();
  #pragma unroll
  for (int i = 0; i < 32; i += 8)
    dst[(size_t)(c0 + ty + i) * rows + r0 + tx] = f2bf(tile[tx][ty + i]);
}

// =====================================================================
// gemmD (R13, best verified): C[M,N] = A[M,K]*Bt[N,K]^T. 128x128 tile,
// BK=64, 256 thr = 4 waves (2x2, wave 64x64). 2-slot LDS = 64 KB,
// depth-1 prefetch (stage t+1 -> slot s^1 under tile t's MFMAs).
// Hazards: stage writes the slot whose reads retired before tile t-1's
// end-BAR (MFMA reg-deps drain lgkm); reads of slot s covered by prev
// VMW(0)+BAR. Swizzles measured conflict-free (SQ_LDS_BANK_CONFLICT=0).
// 14-round falsification matrix: schedule depth/phases, MFMA shape,
// VALU, LDS-BW ratio, occupancy 1/2/4 blocks/CU all moved — the
// ~41.5us/gemm plateau (830 TF, above m102's shape curve for these
// K) did not. This config is the measured optimum.
// =====================================================================
template<int K, bool OUT_BF16>
__global__ __launch_bounds__(256, 2) void gemmD(const ushort_t* __restrict__ A,
                                                const ushort_t* __restrict__ Bt,
                                                void* __restrict__ Cp, int N) {
  constexpr int nt = K / 64;
  __shared__ ushort_t As[2][128 * 64];
  __shared__ ushort_t Bs[2][128 * 64];

  const int tid = threadIdx.x;
  const int nx = gridDim.x;
  const int orig = blockIdx.y * nx + blockIdx.x;
  const int q = (nx * gridDim.y) >> 3;     // grids are multiples of 8
  const int swz = (orig & 7) * q + (orig >> 3);
  const int bx = swz % nx, by = swz / nx;

  const int lane = tid & 63, wv = tid >> 6;
  const int wm = wv >> 1, wn = wv & 1;     // 2M x 2N
  const int lrow = lane & 15, lk = lane >> 4;

  const ushort_t* Ab = A + (size_t)by * 128 * K;
  const ushort_t* Bb = Bt + (size_t)bx * 128 * K;

  // staging: 4 A rounds + 4 B rounds, 32 rows x 128 B each
  const int srow = tid >> 3;
  const int sch = (tid & 7) ^ (srow & 7);
  const ushort_t* pA[4];
  const ushort_t* pB[4];
  #pragma unroll
  for (int r = 0; r < 4; ++r) {
    pA[r] = Ab + (size_t)(r * 32 + srow) * K + sch * 8;
    pB[r] = Bb + (size_t)(r * 32 + srow) * K + sch * 8;
  }
  const int dL = tid * 8;                  // LDS dest elems (+ r*2048)

  auto stage = [&](int s, int adv) {
    #pragma unroll
    for (int r = 0; r < 4; ++r) gload16(pA[r] + adv, (void*)&As[s][r * 2048 + dL]);
    #pragma unroll
    for (int r = 0; r < 4; ++r) gload16(pB[r] + adv, (void*)&Bs[s][r * 2048 + dL]);
  };

  // frag base offsets (ks=1 folds in as ^32 elems; verified pattern)
  int oA[4], oB[4];
  #pragma unroll
  for (int m = 0; m < 4; ++m) {
    const int r = wm * 64 + m * 16 + lrow;
    oA[m] = r * 64 + (lk ^ (r & 7)) * 8;
  }
  #pragma unroll
  for (int n = 0; n < 4; ++n) {
    const int r = wn * 64 + n * 16 + lrow;
    oB[n] = r * 64 + (lk ^ (r & 7)) * 8;
  }

  f32x4 acc[4][4];
  #pragma unroll
  for (int m = 0; m < 4; ++m)
    #pragma unroll
    for (int n = 0; n < 4; ++n)
      acc[m][n] = (f32x4){0.f, 0.f, 0.f, 0.f};

  // prologue: tile0 -> slot0, full drain once
  stage(0, 0);
  VMW(0); SB0(); BAR(); SB0();

  #pragma unroll
  for (int t = 0; t < nt; ++t) {
    const int s = t & 1;
    if (t + 1 < nt) stage(s ^ 1, (t + 1) * 64);   // prefetch under MFMAs
    #pragma unroll
    for (int ks = 0; ks < 2; ++ks) {
      bf16x8 av[4], bv[4];
      #pragma unroll
      for (int m = 0; m < 4; ++m) av[m] = *(const bf16x8*)&As[s][oA[m] ^ (ks * 32)];
      #pragma unroll
      for (int n = 0; n < 4; ++n) bv[n] = *(const bf16x8*)&Bs[s][oB[n] ^ (ks * 32)];
      __builtin_amdgcn_s_setprio(1);
      #pragma unroll
      for (int m = 0; m < 4; ++m)
        #pragma unroll
        for (int n = 0; n < 4; ++n)
          acc[m][n] = __builtin_amdgcn_mfma_f32_16x16x32_bf16(av[m], bv[n], acc[m][n], 0, 0, 0);
      __builtin_amdgcn_s_setprio(0);
    }
    SB0();
    if (t + 1 < nt) VMW(0);              // tile t+1 landed
    BAR(); SB0();
  }

  // epilogue: C/D layout col=lane&15, row=(lane>>4)*4+j
  #pragma unroll
  for (int m = 0; m < 4; ++m) {
    const int row0 = by * 128 + wm * 64 + m * 16 + lk * 4;
    #pragma unroll
    for (int n = 0; n < 4; ++n) {
      const int col = bx * 128 + wn * 64 + n * 16 + lrow;
      #pragma unroll
      for (int j = 0; j < 4; ++j) {
        const size_t idx = (size_t)(row0 + j) * N + col;
        if constexpr (OUT_BF16) ((ushort_t*)Cp)[idx] = f2bf(acc[m][n][j]);
        else                    ((float*)Cp)[idx] = acc[m][n][j];
      }
    }
  }
}

// ---------------- middle: h_all, router softmax, M = sum_p w (x) h ----------------
__global__ __launch_bounds__(256) void middle_kernel(const unsigned short* __restrict__ AH,
                                                     const float* __restrict__ fp,
                                                     const float* __restrict__ femb,
                                                     const float* __restrict__ Wr,
                                                     unsigned short* __restrict__ Mout,
                                                     float* __restrict__ auxout) {
  __shared__ float G[16][16];
  __shared__ float WrBs[128 * 16];
  __shared__ float hs[4][2][128];
  __shared__ float wsm[4][2][16];
  const int tid = threadIdx.x;
  {
    const int n = tid >> 4, j = tid & 15;
    float s = 0.f;
    #pragma unroll
    for (int ds = 0; ds < 64; ++ds) s += femb[n * 64 + ds] * Wr[ds * 16 + j];
    G[n][j] = s;
    #pragma unroll
    for (int k = 0; k < 8; ++k)
      WrBs[tid * 8 + k] = Wr[64 * 16 + tid * 8 + k];
  }
  const int wv = tid >> 6, l = tid & 63;
  const int t = blockIdx.x * 4 + wv;

  float p0[16], p1[16];
  #pragma unroll
  for (int n = 0; n < 16; ++n) {
    p0[n] = fp[t * 16 + n];
    p1[n] = fp[T_TOK * 16 + t * 16 + n];
  }

  float h00 = 0.f, h01 = 0.f, h10 = 0.f, h11 = 0.f;
  const unsigned short* ahrow = AH + (size_t)t * NRCOL;
  #pragma unroll
  for (int n = 0; n < 16; ++n) {
    const unsigned int v = *(const unsigned int*)(ahrow + n * 128 + 2 * l);
    const float a0 = bfbits2f(v & 0xffffu);
    const float a1 = bfbits2f(v >> 16);
    h00 += a0 * p0[n]; h01 += a1 * p0[n];
    h10 += a0 * p1[n]; h11 += a1 * p1[n];
  }
  hs[wv][0][2 * l] = h00; hs[wv][0][2 * l + 1] = h01;
  hs[wv][1][2 * l] = h10; hs[wv][1][2 * l + 1] = h11;
  __syncthreads();

  {
    const int p = l >> 5, seg = (l >> 4) & 1, j = l & 15;
    const float* hp = hs[wv][p] + seg * 64;
    const float* wb = WrBs + seg * 64 * 16 + j;
    float s0 = 0.f, s1 = 0.f, s2 = 0.f, s3 = 0.f;
    #pragma unroll
    for (int r = 0; r < 64; r += 4) {
      s0 += hp[r]     * wb[(r)     * 16];
      s1 += hp[r + 1] * wb[(r + 1) * 16];
      s2 += hp[r + 2] * wb[(r + 2) * 16];
      s3 += hp[r + 3] * wb[(r + 3) * 16];
    }
    float s = (s0 + s1) + (s2 + s3);
    s += __shfl_xor(s, 16, 64);          // combine r-segments
    #pragma unroll
    for (int n = 0; n < 16; ++n) {
      const float fv = p ? p1[n] : p0[n];
      s += fv * G[n][j];
    }
    float mx = s;
    #pragma unroll
    for (int d = 1; d < 16; d <<= 1) mx = fmaxf(mx, __shfl_xor(mx, d, 64));
    const float e = __expf(s - mx);
    float sum = e;
    #pragma unroll
    for (int d = 1; d < 16; d <<= 1) sum += __shfl_xor(sum, d, 64);
    if (seg == 0) wsm[wv][p][j] = e / sum;
  }
  __syncthreads();

  unsigned short* mrow = Mout + (size_t)t * NRCOL;
  #pragma unroll
  for (int n = 0; n < 16; ++n) {
    const float w0 = wsm[wv][0][n], w1 = wsm[wv][1][n];
    const float m0 = w0 * h00 + w1 * h10;
    const float m1 = w0 * h01 + w1 * h11;
    const unsigned int pk = (unsigned)f2bf(m0) | ((unsigned)f2bf(m1) << 16);
    *(unsigned int*)(mrow + n * 128 + 2 * l) = pk;
  }
  if (blockIdx.x == 0 && tid == 0) auxout[0] = 0.f;
}

extern "C" void kernel_launch(void* const* d_in, const int* in_sizes, int n_in,
                              void* d_out, int out_size, void* d_ws, size_t ws_size,
                              hipStream_t stream) {
  const float* x    = (const float*)d_in[0];
  const float* fp   = (const float*)d_in[1];
  const float* fk   = (const float*)d_in[2];
  const float* rk   = (const float*)d_in[3];
  const float* femb = (const float*)d_in[4];
  const float* Wr   = (const float*)d_in[5];
  float* out = (float*)d_out;

  char* ws = (char*)d_ws;
  unsigned short* Xbf = (unsigned short*)ws;
  unsigned short* W1t = (unsigned short*)(ws + 16u * 1024 * 1024);
  unsigned short* Mb  = (unsigned short*)ws;
  unsigned short* W2t = (unsigned short*)(ws + 32u * 1024 * 1024);
  unsigned short* AH  = (unsigned short*)(ws + 36u * 1024 * 1024);

  prep_kernel<<<6144, 256, 0, stream>>>(x, fk, rk, Xbf, W1t, W2t);
  // all_h = Xbf @ W1t^T -> AH bf16 [8192][2048]   (128x128, 2 blocks/CU)
  gemmD<1024, true><<<dim3(NRCOL / 128, T_TOK / 128), 256, 0, stream>>>(Xbf, W1t, AH, NRCOL);
  middle_kernel<<<T_TOK / 4, 256, 0, stream>>>(AH, fp, femb, Wr, Mb, out + 8388608);
  // output = Mb @ W2t^T -> f32 d_out [8192][1024] (128x128, 2 blocks/CU)
  gemmD<2048, false><<<dim3(DIM / 128, T_TOK / 128), 256, 0, stream>>>(Mb, W2t, out, DIM);
}